// Round 5
// baseline (212.997 us; speedup 1.0000x reference)
//
#include <hip/hip_runtime.h>
#include <math.h>

#define NB 2
#define CIN 64
#define DD_ 64
#define HH_ 64
#define WW_ 64
#define NCLS 5
#define LL (DD_*HH_*WW_)   /* 262144 */
#define NMAXG 32
#define TOPKK 13

typedef __attribute__((ext_vector_type(8))) short short8b;
typedef __attribute__((ext_vector_type(4))) float floatx4;

__device__ __forceinline__ float softplusf_(float z){
  return fmaxf(z, 0.f) + log1pf(expf(-fabsf(z)));
}
__device__ __forceinline__ float sigmoidf_(float z){
  return 1.f/(1.f + expf(-z));
}
__device__ __forceinline__ unsigned tobf_u_(float f){
  unsigned u = __float_as_uint(f);
  return (u + 0x7fffu + ((u>>16)&1u)) >> 16;
}
__device__ __forceinline__ short tobf_(float f){
  return (short)tobf_u_(f);
}

// ---------------- Phase 0: build MFMA A-fragments (d-pair packed)
// slice = ((rr*2+s)*3+kw)*4+cc, rr in 0..3
// A[m][k]: m<8 -> outch m, kd=rr;  m>=8 -> outch m-8, kd=rr-1 (zero if kd out of 0..2)
// k = khl*16 + cl ; s=0: kh=khl(0,1); s=1: khl0->kh2, khl1->zero
__global__ __launch_bounds__(256) void wtrans_kernel(
    const float* __restrict__ cls_w, const float* __restrict__ off_w,
    short* __restrict__ wA)
{
  int idx = blockIdx.x*256 + threadIdx.x;
  if (idx >= 96*64) return;
  int slice = idx >> 6; int lane = idx & 63;
  int cc = slice & 3; int r2 = slice >> 2;
  int kw = r2 - 3*(r2/3); int r3 = r2/3;
  int s  = r3 & 1;        int rr = r3 >> 1;
  int m = lane & 15, g = lane >> 4;
  int outch = m & 7;
  int kd = (m < 8) ? rr : rr - 1;
  short8b out;
  #pragma unroll
  for (int i=0;i<8;++i){
    int k = g*8 + i; int khl = k >> 4; int cl = k & 15;
    int kh = (s==0) ? khl : (khl==0 ? 2 : -1);
    float wv = 0.f;
    if (kd >= 0 && kd <= 2 && kh >= 0){
      int c = cc*16 + cl;
      if (outch < NCLS) wv = cls_w[(outch*CIN + c)*27 + (kd*3+kh)*3 + kw];
      else              wv = off_w[((outch-NCLS)*CIN + c)*27 + (kd*3+kh)*3 + kw];
    }
    out[i] = tobf_(wv);
  }
  *(short8b*)(wA + (size_t)idx*8) = out;
}

// ---------------- Phase A: MFMA conv, d-pair packed. Block: 4d x 4h x 64w, 512 thr.
__global__ __launch_bounds__(512, 4) void conv_mfma_kernel(
    const float* __restrict__ feat,
    const short* __restrict__ wA,
    const float* __restrict__ cls_b, const float* __restrict__ off_b,
    float* __restrict__ logits_ws,   // [B][5][L]
    float* __restrict__ centers_ws,  // [B][L][4]
    float* __restrict__ bg_sum,      // [0]=bg, [1]=maxoff bits
    unsigned* __restrict__ moff_u)
{
  __shared__ short xs[36*68*16];     // [row=6d'*6h'][wp 0..67][16c] bf16, 78336 B
  __shared__ float bsum[8];

  const int tid = threadIdx.x;
  const int lane = tid & 63, wv = tid >> 6;
  const int col = lane & 15, g = lane >> 4;
  const int chalf = g & 1, khl = g >> 1;
  const int h0 = blockIdx.x*4, d0 = blockIdx.y*4, b = blockIdx.z;

  // zero the w-halo slots (wp 0 and 65) once
  for (int idx = tid; idx < 36*32; idx += 512){
    int row = idx >> 5; int rr2 = idx & 31;
    int wp = (rr2 < 16) ? 0 : 65;
    xs[(row*68 + wp)*16 + (rr2 & 15)] = 0;
  }

  floatx4 acc[4];
  #pragma unroll
  for (int t=0;t<4;++t) acc[t] = (floatx4){0.f,0.f,0.f,0.f};

  const short8b* wAv = (const short8b*)wA;

  for (int cc=0; cc<4; ++cc){
    if (cc) __syncthreads();
    // ---- stage: thread = (row, wp, half). 8 strided loads -> one ds_write_b128.
    #pragma unroll 1
    for (int it=0; it<9; ++it){
      int idx = it*512 + tid;            // 0..4607 = 36 rows * 64 wp * 2 half
      int half = idx & 1;
      int wp1  = ((idx>>1) & 63) + 1;    // 1..64
      int row  = idx >> 7;               // 0..35
      int row_d = row/6;
      int row_h = row - row_d*6;
      int d_ = d0 - 1 + row_d;
      int h_ = h0 - 1 + row_h;
      bool inb = (d_>=0 && d_<DD_ && h_>=0 && h_<HH_);
      const float* pp = feat + ((((size_t)b*CIN + cc*16 + half*8)*DD_ + (inb?d_:0))*HH_ + (inb?h_:0))*WW_ + (wp1-1);
      float f[8];
      #pragma unroll
      for (int j=0;j<8;++j) f[j] = inb ? pp[(size_t)j*LL] : 0.f;
      uint4 pk;
      pk.x = (tobf_u_(f[1])<<16) | tobf_u_(f[0]);
      pk.y = (tobf_u_(f[3])<<16) | tobf_u_(f[2]);
      pk.z = (tobf_u_(f[5])<<16) | tobf_u_(f[4]);
      pk.w = (tobf_u_(f[7])<<16) | tobf_u_(f[6]);
      int off = (row*68 + wp1)*16 + ((half ^ ((wp1>>2)&1))<<3);
      *(uint4*)(xs + off) = pk;
    }
    __syncthreads();
    // ---- compute: 24 A-slices x 4 tiles per wave
    #pragma unroll 1
    for (int rr=0; rr<4; ++rr){
      #pragma unroll
      for (int s=0;s<2;++s){
        #pragma unroll
        for (int kw=0;kw<3;++kw){
          int slice = ((rr*2+s)*3+kw)*4+cc;
          short8b a = wAv[slice*64 + lane];
          int khe = s ? 2 : khl;
          #pragma unroll
          for (int t=0;t<4;++t){
            int tile = wv*4 + t;             // 0..31
            int dp = tile>>4, hl = (tile>>2)&3, wq = tile&3;
            int row = (2*dp + rr)*6 + hl + khe;
            int wp = wq*16 + col + kw;
            int sidx = (row*68 + wp)*16 + ((chalf ^ ((wp>>2)&1))<<3);
            short8b bfr = *(const short8b*)(xs + sidx);
            acc[t] = __builtin_amdgcn_mfma_f32_16x16x32_bf16(a, bfr, acc[t], 0,0,0);
          }
        }
      }
    }
  }

  // ---- epilogue: C row m = g*4+j: g0: ch0-3@d, g1: ch4-7@d, g2: ch0-3@d+1, g3: ch4-7@d+1
  float bg = 0.f;
  float om = 0.f;
  #pragma unroll
  for (int t=0;t<4;++t){
    int tile = wv*4 + t;
    int dp = tile>>4, hl = (tile>>2)&3, wq = tile&3;
    int d = d0 + 2*dp + (g>>1), h = h0+hl, w = wq*16 + col;
    size_t l = (size_t)d*4096 + (size_t)h*64 + w;
    if ((g&1) == 0){
      #pragma unroll
      for (int j=0;j<4;++j){
        float z = acc[t][j] + cls_b[j];
        logits_ws[(size_t)(b*NCLS+j)*LL + l] = z;
        float pr = sigmoidf_(z);
        bg += 0.75f*pr*pr*softplusf_(z);
      }
    } else {
      float z = acc[t][0] + cls_b[4];
      logits_ws[(size_t)(b*NCLS+4)*LL + l] = z;
      float pr = sigmoidf_(z);
      bg += 0.75f*pr*pr*softplusf_(z);
      float o0 = acc[t][1] + off_b[0];
      float o1 = acc[t][2] + off_b[1];
      float o2 = acc[t][3] + off_b[2];
      om = fmaxf(om, fmaxf(fabsf(o0), fmaxf(fabsf(o1), fabsf(o2))));
      float4 ctr;
      ctr.x = ((float)d+0.5f)*2.f + o0;
      ctr.y = ((float)h+0.5f)*2.f + o1;
      ctr.z = ((float)w+0.5f)*2.f + o2;
      ctr.w = 0.f;
      *(float4*)(centers_ws + ((size_t)b*LL + l)*4) = ctr;
    }
  }
  #pragma unroll
  for (int off=32;off;off>>=1){
    bg += __shfl_down(bg, off);
    om = fmaxf(om, __shfl_xor(om, off));
  }
  if (lane == 0){
    bsum[wv] = bg;
    atomicMax(moff_u, __float_as_uint(om));
  }
  __syncthreads();
  if (tid == 0){
    float s = 0.f;
    #pragma unroll
    for (int i=0;i<8;++i) s += bsum[i];
    atomicAdd(bg_sum, s);
  }
}

// ---------------- Phase B: exact bounding-box top-13 per (b,n). Grid 64 x 256thr.
__global__ __launch_bounds__(256) void topk_box_kernel(
    const float* __restrict__ logits_ws, const float* __restrict__ centers_ws,
    const float* __restrict__ labels,
    const unsigned* __restrict__ moff_u,
    float* __restrict__ tv, int* __restrict__ ti)   // [64][13]
{
  const int bn = blockIdx.x;
  const int b = bn >> 5, n = bn & 31;
  const int tid = threadIdx.x;

  const float* lb = labels + (b*NMAXG + n)*5;
  const float tx = lb[0], ty = lb[1], tz = lb[2];
  const float cf = lb[3];
  const float sg = lb[4];
  const int lab = (cf == -100.f) ? 0 : (int)cf;
  const float m6 = -3.f/(sg*sg);
  const float moff = __uint_as_float(*moff_u);
  // align > 1e-9 requires m6*d2 >= -20.8 -> d <= sqrt(20.8/3)*sg = 2.6332*sg
  const float R = 2.6336f*sg + moff + 0.05f;

  int i0d = (int)ceilf((tx - R - 1.f)*0.5f); if (i0d < 0) i0d = 0;
  int i1d = (int)floorf((tx + R - 1.f)*0.5f); if (i1d > 63) i1d = 63;
  int i0h = (int)ceilf((ty - R - 1.f)*0.5f); if (i0h < 0) i0h = 0;
  int i1h = (int)floorf((ty + R - 1.f)*0.5f); if (i1h > 63) i1h = 63;
  int i0w = (int)ceilf((tz - R - 1.f)*0.5f); if (i0w < 0) i0w = 0;
  int i1w = (int)floorf((tz + R - 1.f)*0.5f); if (i1w > 63) i1w = 63;
  int nd = i1d-i0d+1, nh = i1h-i0h+1, nw = i1w-i0w+1;
  int total = (nd>0 && nh>0 && nw>0) ? nd*nh*nw : 0;

  const float* lg = logits_ws + (size_t)(b*NCLS + lab)*LL;
  const float* cb = centers_ws + (size_t)b*LL*4;

  float v[13]; int ix[13];
  #pragma unroll
  for (int j=0;j<13;++j){ v[j]=-1.f; ix[j]=0x7fffffff; }

  for (int idx = tid; idx < total; idx += 256){
    int r = idx;
    int wi = r % nw; r /= nw;
    int hi = r % nh; int di = r / nh;
    int l = (i0d+di)*4096 + (i0h+hi)*64 + (i0w+wi);
    float4 c4 = *(const float4*)(cb + (size_t)l*4);
    float dx = c4.x-tx, dy = c4.y-ty, dz = c4.z-tz;
    float e = m6*(dx*dx + dy*dy + dz*dz);
    if (e < -20.8f) continue;
    float a = sigmoidf_(lg[l]) * expf(e);
    if (a > v[12]){
      float cv = a; int ci = l;
      #pragma unroll
      for (int j=0;j<13;++j){
        bool take = (cv > v[j]) || (cv == v[j] && ci < ix[j]);
        float nv = take ? cv : v[j];  float ov = take ? v[j] : cv;
        int   ni = take ? ci : ix[j]; int   oi = take ? ix[j] : ci;
        v[j]=nv; ix[j]=ni; cv=ov; ci=oi;
      }
    }
  }

  // wave merge: 13 butterfly-pop rounds
  const int lane = tid & 63, wvi = tid >> 6;
  float mv = -2.f; int mi = 0x7fffffff;
  #pragma unroll 1
  for (int k=0;k<13;++k){
    float bv = v[0]; int bi = ix[0]; int bl = lane;
    #pragma unroll
    for (int off=32; off; off>>=1){
      float ov2 = __shfl_xor(bv, off);
      int oi = __shfl_xor(bi, off);
      int ol = __shfl_xor(bl, off);
      if (ov2 > bv || (ov2 == bv && oi < bi)){ bv=ov2; bi=oi; bl=ol; }
    }
    if (lane == k){ mv = bv; mi = bi; }
    if (lane == bl){
      #pragma unroll
      for (int j=0;j<12;++j){ v[j]=v[j+1]; ix[j]=ix[j+1]; }
      v[12] = -2.f; ix[12] = 0x7fffffff;
    }
  }
  __shared__ float sv2[4*13]; __shared__ int si2[4*13];
  if (lane < 13){ sv2[wvi*13+lane] = mv; si2[wvi*13+lane] = mi; }
  __syncthreads();
  if (wvi == 0){
    float v2 = -2.f; int i2 = 0x7fffffff;
    if (lane < 52){ v2 = sv2[lane]; i2 = si2[lane]; }
    #pragma unroll 1
    for (int k=0;k<13;++k){
      float bv = v2; int bi = i2; int bl = lane;
      #pragma unroll
      for (int off=32; off; off>>=1){
        float ov2 = __shfl_xor(bv, off);
        int oi = __shfl_xor(bi, off);
        int ol = __shfl_xor(bl, off);
        if (ov2 > bv || (ov2 == bv && oi < bi)){ bv=ov2; bi=oi; bl=ol; }
      }
      if (lane == 0){
        tv[bn*TOPKK + k] = bv;
        ti[bn*TOPKK + k] = bi;
      }
      if (lane == bl) v2 = -2.f;
    }
  }
}

// ---------------- Phase C: parallel candidate resolution via LDS hash table
__global__ __launch_bounds__(512) void finalize_kernel(
    const float* __restrict__ logits_ws, const float* __restrict__ centers_ws,
    const float* __restrict__ labels,
    const float* __restrict__ tv, const int* __restrict__ ti,
    const float* __restrict__ bg_sum, float* __restrict__ out)
{
  const int tid = threadIdx.x;   // 512
  __shared__ float gx[32], gy[32], gz[32], gs[32];
  __shared__ int glab[32], gvalid[32];
  __shared__ int hkey[1024], hcnt[1024], hmin[1024];
  __shared__ unsigned maxA[32], maxI[32];
  __shared__ float accD, accC;
  if (tid==0){ accD=0.f; accC=0.f; }

  for (int b=0;b<NB;++b){
    for (int i=tid;i<1024;i+=512){ hkey[i]=-1; hcnt[i]=0; hmin[i]=0x7fffffff; }
    if (tid<32){
      const float* lb = labels + (b*NMAXG + tid)*5;
      gx[tid]=lb[0]; gy[tid]=lb[1]; gz[tid]=lb[2];
      float cf = lb[3]; gs[tid]=lb[4];
      int val = (cf != -100.f);
      gvalid[tid]=val; glab[tid]= val ? (int)cf : 0;
      maxA[tid]=0u; maxI[tid]=0u;
    }
    __syncthreads();

    const int e = tid;
    bool ok = false; int l = -1; int n = 0;
    if (e < 416){
      n = e/13; int k = e - 13*n;
      float v = tv[(b*NMAXG+n)*TOPKK + k];
      l = ti[(b*NMAXG+n)*TOPKK + k];
      ok = gvalid[n] && (v > 1e-9f);
    }
    int slot = -1;
    if (ok){
      unsigned h = (((unsigned)l * 2654435761u) >> 20) & 1023u;
      for (;;){
        int prev = atomicCAS(&hkey[h], -1, l);
        if (prev == -1 || prev == l){ slot = (int)h; break; }
        h = (h+1) & 1023u;
      }
      atomicAdd(&hcnt[slot], 1);
      atomicMin(&hmin[slot], e);
    }
    __syncthreads();

    bool first = ok && (hmin[slot] == e);
    float a=0.f, iou=0.f; int nstar=0;
    if (first){
      float px = centers_ws[((size_t)b*LL + l)*4 + 0];
      float py = centers_ws[((size_t)b*LL + l)*4 + 1];
      float pz = centers_ws[((size_t)b*LL + l)*4 + 2];
      if (hcnt[slot] == 1){
        nstar = n;
      } else {
        float best = -1.f; int bidx = 0;
        for (int nn=0;nn<32;++nn){
          float dx=gx[nn]-px, dy=gy[nn]-py, dz=gz[nn]-pz;
          float d2 = dx*dx+dy*dy+dz*dz;
          float io = expf(-d2/(2.f*gs[nn]*gs[nn]));
          if (io > best){ best=io; bidx=nn; }
        }
        nstar = bidx;
      }
      float dx=gx[nstar]-px, dy=gy[nstar]-py, dz=gz[nstar]-pz;
      float d2 = dx*dx+dy*dy+dz*dz;
      float sgv = gs[nstar];
      iou = expf(-d2/(2.f*sgv*sgv));
      float z = logits_ws[(size_t)(b*NCLS + glab[nstar])*LL + l];
      a = sigmoidf_(z) * expf(-3.f*d2/(sgv*sgv));
      atomicMax(&maxA[nstar], __float_as_uint(a));
      atomicMax(&maxI[nstar], __float_as_uint(iou));
    }
    __syncthreads();

    if (first){
      float mA = __uint_as_float(maxA[nstar]);
      float mI = __uint_as_float(maxI[nstar]);
      float score = a*mI/(mA + 1e-9f);
      float z = logits_ws[(size_t)(b*NCLS + glab[nstar])*LL + l];
      float p = sigmoidf_(z);
      float t2 = log1pf(expf(-fabsf(z)));
      float spz = fmaxf(z,0.f) + t2;
      float spm = fmaxf(-z,0.f) + t2;
      float corr = score*(score*spm + (1.f-score)*spz) - 0.75f*p*p*spz;
      float reg  = (1.f - iou)*score;
      atomicAdd(&accD, score);
      atomicAdd(&accC, corr + reg);
    }
    __syncthreads();
  }
  if (tid==0) out[0] = (bg_sum[0] + accC) / accD;
}

extern "C" void kernel_launch(void* const* d_in, const int* in_sizes, int n_in,
                              void* d_out, int out_size, void* d_ws, size_t ws_size,
                              hipStream_t stream) {
  const float* feat  = (const float*)d_in[0];
  const float* cls_w = (const float*)d_in[1];
  const float* cls_b = (const float*)d_in[2];
  const float* off_w = (const float*)d_in[3];
  const float* off_b = (const float*)d_in[4];
  const float* labels= (const float*)d_in[5];
  float* out = (float*)d_out;

  float* logits_ws  = (float*)d_ws;                              // 2*5*L
  float* centers_ws = logits_ws + (size_t)NB*NCLS*LL;            // 2*L*4
  float* tv = centers_ws + (size_t)NB*LL*4;                      // 64*13
  int*   ti = (int*)(tv + 64*TOPKK);
  float* bg = (float*)(ti + 64*TOPKK);                           // [0]=bg,[1]=maxoff
  short* wA = (short*)(bg + 16);                                 // 96*64*8 bf16

  hipMemsetAsync(bg, 0, 8, stream);

  wtrans_kernel<<<24, 256, 0, stream>>>(cls_w, off_w, wA);
  conv_mfma_kernel<<<dim3(16,16,2), 512, 0, stream>>>(
      feat, wA, cls_b, off_b, logits_ws, centers_ws, bg, (unsigned*)(bg+1));
  topk_box_kernel<<<64, 256, 0, stream>>>(
      logits_ws, centers_ws, labels, (const unsigned*)(bg+1), tv, ti);
  finalize_kernel<<<1, 512, 0, stream>>>(
      logits_ws, centers_ws, labels, tv, ti, bg, out);
}

// Round 6
// 205.987 us; speedup vs baseline: 1.0340x; 1.0340x over previous
//
#include <hip/hip_runtime.h>
#include <math.h>

#define NB 2
#define CIN 64
#define DD_ 64
#define HH_ 64
#define WW_ 64
#define NCLS 5
#define LL (DD_*HH_*WW_)   /* 262144 */
#define NMAXG 32
#define TOPKK 13

typedef __attribute__((ext_vector_type(8))) short short8b;
typedef __attribute__((ext_vector_type(4))) float floatx4;

__device__ __forceinline__ float softplusf_(float z){
  return fmaxf(z, 0.f) + log1pf(expf(-fabsf(z)));
}
__device__ __forceinline__ float sigmoidf_(float z){
  return 1.f/(1.f + expf(-z));
}
__device__ __forceinline__ unsigned tobf_u_(float f){
  unsigned u = __float_as_uint(f);
  return (u + 0x7fffu + ((u>>16)&1u)) >> 16;
}
__device__ __forceinline__ short tobf_(float f){
  return (short)tobf_u_(f);
}

// ---------------- Phase 0: build MFMA A-fragments (d-pair packed) + zero accumulators
// slice = ((rr*2+s)*3+kw)*4+cc, rr in 0..3
// A[m][k]: m<8 -> outch m, kd=rr;  m>=8 -> outch m-8, kd=rr-1 (zero if kd out of 0..2)
// k = khl*16 + cl ; s=0: kh=khl(0,1); s=1: khl0->kh2, khl1->zero
__global__ __launch_bounds__(256) void wtrans_kernel(
    const float* __restrict__ cls_w, const float* __restrict__ off_w,
    short* __restrict__ wA, float* __restrict__ bgz)
{
  if (blockIdx.x == 0 && threadIdx.x < 2) bgz[threadIdx.x] = 0.f;  // bg_sum, moff
  int idx = blockIdx.x*256 + threadIdx.x;
  if (idx >= 96*64) return;
  int slice = idx >> 6; int lane = idx & 63;
  int cc = slice & 3; int r2 = slice >> 2;
  int kw = r2 - 3*(r2/3); int r3 = r2/3;
  int s  = r3 & 1;        int rr = r3 >> 1;
  int m = lane & 15, g = lane >> 4;
  int outch = m & 7;
  int kd = (m < 8) ? rr : rr - 1;
  short8b out;
  #pragma unroll
  for (int i=0;i<8;++i){
    int k = g*8 + i; int khl = k >> 4; int cl = k & 15;
    int kh = (s==0) ? khl : (khl==0 ? 2 : -1);
    float wv = 0.f;
    if (kd >= 0 && kd <= 2 && kh >= 0){
      int c = cc*16 + cl;
      if (outch < NCLS) wv = cls_w[(outch*CIN + c)*27 + (kd*3+kh)*3 + kw];
      else              wv = off_w[((outch-NCLS)*CIN + c)*27 + (kd*3+kh)*3 + kw];
    }
    out[i] = tobf_(wv);
  }
  *(short8b*)(wA + (size_t)idx*8) = out;
}

// ---------------- Phase A: MFMA conv, d-pair packed. Block: 4d x 4h x 64w, 512 thr.
__global__ __launch_bounds__(512, 4) void conv_mfma_kernel(
    const float* __restrict__ feat,
    const short* __restrict__ wA,
    const float* __restrict__ cls_b, const float* __restrict__ off_b,
    float* __restrict__ logits_ws,   // [B][5][L]
    float* __restrict__ centers_ws,  // [B][L][4]
    float* __restrict__ bg_sum,      // [0]=bg
    unsigned* __restrict__ moff_u)   // [0]=max|offset| bits
{
  __shared__ short xs[36*68*16];     // [row=6d'*6h'][wp 0..67][16c] bf16, 78336 B
  __shared__ float bsum[8];

  const int tid = threadIdx.x;
  const int lane = tid & 63, wv = tid >> 6;
  const int col = lane & 15, g = lane >> 4;
  const int chalf = g & 1, khl = g >> 1;
  const int h0 = blockIdx.x*4, d0 = blockIdx.y*4, b = blockIdx.z;

  // zero the w-halo slots (wp 0 and 65) once
  for (int idx = tid; idx < 36*32; idx += 512){
    int row = idx >> 5; int rr2 = idx & 31;
    int wp = (rr2 < 16) ? 0 : 65;
    xs[(row*68 + wp)*16 + (rr2 & 15)] = 0;
  }

  floatx4 acc[4];
  #pragma unroll
  for (int t=0;t<4;++t) acc[t] = (floatx4){0.f,0.f,0.f,0.f};

  const short8b* wAv = (const short8b*)wA;
  const bool edge = (d0==0) || (d0==DD_-4) || (h0==0) || (h0==HH_-4);

  #pragma unroll 1
  for (int cc=0; cc<4; ++cc){
    if (cc) __syncthreads();
    // ---- stage: thread = (row, wp, half). 8 strided loads -> one ds_write_b128.
    if (!edge){
      #pragma unroll 3
      for (int it=0; it<9; ++it){
        int idx = it*512 + tid;            // 36 rows * 64 wp * 2 half
        int half = idx & 1;
        int wp1  = ((idx>>1) & 63) + 1;    // 1..64
        int row  = idx >> 7;               // 0..35
        int row_d = row/6;
        int row_h = row - row_d*6;
        const float* pp = feat + ((((size_t)b*CIN + cc*16 + half*8)*DD_ + (d0-1+row_d))*HH_ + (h0-1+row_h))*WW_ + (wp1-1);
        float f[8];
        #pragma unroll
        for (int j=0;j<8;++j) f[j] = pp[(size_t)j*LL];
        uint4 pk;
        pk.x = (tobf_u_(f[1])<<16) | tobf_u_(f[0]);
        pk.y = (tobf_u_(f[3])<<16) | tobf_u_(f[2]);
        pk.z = (tobf_u_(f[5])<<16) | tobf_u_(f[4]);
        pk.w = (tobf_u_(f[7])<<16) | tobf_u_(f[6]);
        int off = (row*68 + wp1)*16 + ((half ^ ((wp1>>2)&1))<<3);
        *(uint4*)(xs + off) = pk;
      }
    } else {
      #pragma unroll 3
      for (int it=0; it<9; ++it){
        int idx = it*512 + tid;
        int half = idx & 1;
        int wp1  = ((idx>>1) & 63) + 1;
        int row  = idx >> 7;
        int row_d = row/6;
        int row_h = row - row_d*6;
        int d_ = d0 - 1 + row_d;
        int h_ = h0 - 1 + row_h;
        bool inb = (d_>=0 && d_<DD_ && h_>=0 && h_<HH_);
        const float* pp = feat + ((((size_t)b*CIN + cc*16 + half*8)*DD_ + (inb?d_:0))*HH_ + (inb?h_:0))*WW_ + (wp1-1);
        float f[8];
        #pragma unroll
        for (int j=0;j<8;++j) f[j] = inb ? pp[(size_t)j*LL] : 0.f;
        uint4 pk;
        pk.x = (tobf_u_(f[1])<<16) | tobf_u_(f[0]);
        pk.y = (tobf_u_(f[3])<<16) | tobf_u_(f[2]);
        pk.z = (tobf_u_(f[5])<<16) | tobf_u_(f[4]);
        pk.w = (tobf_u_(f[7])<<16) | tobf_u_(f[6]);
        int off = (row*68 + wp1)*16 + ((half ^ ((wp1>>2)&1))<<3);
        *(uint4*)(xs + off) = pk;
      }
    }
    __syncthreads();
    // ---- compute: 4 rr x (6 A-slices prefetched) x 4 tiles per wave
    #pragma unroll 1
    for (int rr=0; rr<4; ++rr){
      short8b areg[6];
      #pragma unroll
      for (int q=0;q<6;++q)
        areg[q] = wAv[((rr*6+q)*4+cc)*64 + lane];
      #pragma unroll
      for (int s=0;s<2;++s){
        #pragma unroll
        for (int kw=0;kw<3;++kw){
          short8b a = areg[s*3+kw];
          int khe = s ? 2 : khl;
          #pragma unroll
          for (int t=0;t<4;++t){
            int tile = wv*4 + t;             // 0..31
            int dp = tile>>4, hl = (tile>>2)&3, wq = tile&3;
            int row = (2*dp + rr)*6 + hl + khe;
            int wp = wq*16 + col + kw;
            int sidx = (row*68 + wp)*16 + ((chalf ^ ((wp>>2)&1))<<3);
            short8b bfr = *(const short8b*)(xs + sidx);
            acc[t] = __builtin_amdgcn_mfma_f32_16x16x32_bf16(a, bfr, acc[t], 0,0,0);
          }
        }
      }
    }
  }

  // ---- epilogue: C row m = g*4+j: g0: ch0-3@d, g1: ch4-7@d, g2: ch0-3@d+1, g3: ch4-7@d+1
  float bg = 0.f;
  float om = 0.f;
  #pragma unroll
  for (int t=0;t<4;++t){
    int tile = wv*4 + t;
    int dp = tile>>4, hl = (tile>>2)&3, wq = tile&3;
    int d = d0 + 2*dp + (g>>1), h = h0+hl, w = wq*16 + col;
    size_t l = (size_t)d*4096 + (size_t)h*64 + w;
    if ((g&1) == 0){
      #pragma unroll
      for (int j=0;j<4;++j){
        float z = acc[t][j] + cls_b[j];
        logits_ws[(size_t)(b*NCLS+j)*LL + l] = z;
        float pr = sigmoidf_(z);
        bg += 0.75f*pr*pr*softplusf_(z);
      }
    } else {
      float z = acc[t][0] + cls_b[4];
      logits_ws[(size_t)(b*NCLS+4)*LL + l] = z;
      float pr = sigmoidf_(z);
      bg += 0.75f*pr*pr*softplusf_(z);
      float o0 = acc[t][1] + off_b[0];
      float o1 = acc[t][2] + off_b[1];
      float o2 = acc[t][3] + off_b[2];
      om = fmaxf(om, fmaxf(fabsf(o0), fmaxf(fabsf(o1), fabsf(o2))));
      float4 ctr;
      ctr.x = ((float)d+0.5f)*2.f + o0;
      ctr.y = ((float)h+0.5f)*2.f + o1;
      ctr.z = ((float)w+0.5f)*2.f + o2;
      ctr.w = 0.f;
      *(float4*)(centers_ws + ((size_t)b*LL + l)*4) = ctr;
    }
  }
  #pragma unroll
  for (int off=32;off;off>>=1){
    bg += __shfl_down(bg, off);
    om = fmaxf(om, __shfl_xor(om, off));
  }
  if (lane == 0){
    bsum[wv] = bg;
    atomicMax(moff_u, __float_as_uint(om));
  }
  __syncthreads();
  if (tid == 0){
    float s = 0.f;
    #pragma unroll
    for (int i=0;i<8;++i) s += bsum[i];
    atomicAdd(bg_sum, s);
  }
}

// ---------------- Phase B: exact bounding-box top-13 per (b,n). Grid 64 x 256thr.
__global__ __launch_bounds__(256) void topk_box_kernel(
    const float* __restrict__ logits_ws, const float* __restrict__ centers_ws,
    const float* __restrict__ labels,
    const unsigned* __restrict__ moff_u,
    float* __restrict__ tv, int* __restrict__ ti)   // [64][13]
{
  const int bn = blockIdx.x;
  const int b = bn >> 5, n = bn & 31;
  const int tid = threadIdx.x;

  const float* lb = labels + (b*NMAXG + n)*5;
  const float tx = lb[0], ty = lb[1], tz = lb[2];
  const float cf = lb[3];
  const float sg = lb[4];
  const int lab = (cf == -100.f) ? 0 : (int)cf;
  const float m6 = -3.f/(sg*sg);
  const float moff = __uint_as_float(*moff_u);
  // align > 1e-9 requires m6*d2 >= -20.8 -> d <= sqrt(20.8/3)*sg = 2.6332*sg
  const float R = 2.6336f*sg + moff + 0.05f;

  int i0d = (int)ceilf((tx - R - 1.f)*0.5f); if (i0d < 0) i0d = 0;
  int i1d = (int)floorf((tx + R - 1.f)*0.5f); if (i1d > 63) i1d = 63;
  int i0h = (int)ceilf((ty - R - 1.f)*0.5f); if (i0h < 0) i0h = 0;
  int i1h = (int)floorf((ty + R - 1.f)*0.5f); if (i1h > 63) i1h = 63;
  int i0w = (int)ceilf((tz - R - 1.f)*0.5f); if (i0w < 0) i0w = 0;
  int i1w = (int)floorf((tz + R - 1.f)*0.5f); if (i1w > 63) i1w = 63;
  int nd = i1d-i0d+1, nh = i1h-i0h+1, nw = i1w-i0w+1;
  int total = (nd>0 && nh>0 && nw>0) ? nd*nh*nw : 0;

  const float* lg = logits_ws + (size_t)(b*NCLS + lab)*LL;
  const float* cb = centers_ws + (size_t)b*LL*4;

  float v[13]; int ix[13];
  #pragma unroll
  for (int j=0;j<13;++j){ v[j]=-1.f; ix[j]=0x7fffffff; }

  for (int idx = tid; idx < total; idx += 256){
    int r = idx;
    int wi = r % nw; r /= nw;
    int hi = r % nh; int di = r / nh;
    int l = (i0d+di)*4096 + (i0h+hi)*64 + (i0w+wi);
    float4 c4 = *(const float4*)(cb + (size_t)l*4);
    float dx = c4.x-tx, dy = c4.y-ty, dz = c4.z-tz;
    float e = m6*(dx*dx + dy*dy + dz*dz);
    if (e < -20.8f) continue;
    float a = sigmoidf_(lg[l]) * expf(e);
    if (a > v[12]){
      float cv = a; int ci = l;
      #pragma unroll
      for (int j=0;j<13;++j){
        bool take = (cv > v[j]) || (cv == v[j] && ci < ix[j]);
        float nv = take ? cv : v[j];  float ov = take ? v[j] : cv;
        int   ni = take ? ci : ix[j]; int   oi = take ? ix[j] : ci;
        v[j]=nv; ix[j]=ni; cv=ov; ci=oi;
      }
    }
  }

  // wave merge: 13 butterfly-pop rounds
  const int lane = tid & 63, wvi = tid >> 6;
  float mv = -2.f; int mi = 0x7fffffff;
  #pragma unroll 1
  for (int k=0;k<13;++k){
    float bv = v[0]; int bi = ix[0]; int bl = lane;
    #pragma unroll
    for (int off=32; off; off>>=1){
      float ov2 = __shfl_xor(bv, off);
      int oi = __shfl_xor(bi, off);
      int ol = __shfl_xor(bl, off);
      if (ov2 > bv || (ov2 == bv && oi < bi)){ bv=ov2; bi=oi; bl=ol; }
    }
    if (lane == k){ mv = bv; mi = bi; }
    if (lane == bl){
      #pragma unroll
      for (int j=0;j<12;++j){ v[j]=v[j+1]; ix[j]=ix[j+1]; }
      v[12] = -2.f; ix[12] = 0x7fffffff;
    }
  }
  __shared__ float sv2[4*13]; __shared__ int si2[4*13];
  if (lane < 13){ sv2[wvi*13+lane] = mv; si2[wvi*13+lane] = mi; }
  __syncthreads();
  if (wvi == 0){
    float v2 = -2.f; int i2 = 0x7fffffff;
    if (lane < 52){ v2 = sv2[lane]; i2 = si2[lane]; }
    #pragma unroll 1
    for (int k=0;k<13;++k){
      float bv = v2; int bi = i2; int bl = lane;
      #pragma unroll
      for (int off=32; off; off>>=1){
        float ov2 = __shfl_xor(bv, off);
        int oi = __shfl_xor(bi, off);
        int ol = __shfl_xor(bl, off);
        if (ov2 > bv || (ov2 == bv && oi < bi)){ bv=ov2; bi=oi; bl=ol; }
      }
      if (lane == 0){
        tv[bn*TOPKK + k] = bv;
        ti[bn*TOPKK + k] = bi;
      }
      if (lane == bl) v2 = -2.f;
    }
  }
}

// ---------------- Phase C: both batches in one 1024-thread pass, LDS hash table
__global__ __launch_bounds__(1024) void finalize_kernel(
    const float* __restrict__ logits_ws, const float* __restrict__ centers_ws,
    const float* __restrict__ labels,
    const float* __restrict__ tv, const int* __restrict__ ti,
    const float* __restrict__ bg_sum, float* __restrict__ out)
{
  const int tid = threadIdx.x;   // 1024
  __shared__ float gx[64], gy[64], gz[64], gs[64];
  __shared__ int glab[64], gvalid[64];
  __shared__ int hkey[2048], hcnt[2048], hmin[2048];
  __shared__ unsigned maxA[64], maxI[64];
  __shared__ float accD, accC;
  if (tid==0){ accD=0.f; accC=0.f; }
  for (int i=tid;i<2048;i+=1024){ hkey[i]=-1; hcnt[i]=0; hmin[i]=0x7fffffff; }
  if (tid<64){
    const float* lb = labels + tid*5;   // tid = b*32+n
    gx[tid]=lb[0]; gy[tid]=lb[1]; gz[tid]=lb[2];
    float cf = lb[3]; gs[tid]=lb[4];
    int val = (cf != -100.f);
    gvalid[tid]=val; glab[tid]= val ? (int)cf : 0;
    maxA[tid]=0u; maxI[tid]=0u;
  }
  __syncthreads();

  const int e = tid;
  bool ok = false; int l = -1; int n = 0; int b = 0;
  if (e < 2*416){
    b = (e >= 416) ? 1 : 0;
    int eb = e - 416*b;
    n = eb/13; int k = eb - 13*n;
    float v = tv[(b*NMAXG+n)*TOPKK + k];
    l = ti[(b*NMAXG+n)*TOPKK + k];
    ok = gvalid[b*32+n] && (v > 1e-9f);
  }
  int slot = -1;
  if (ok){
    unsigned h = (((unsigned)l * 2654435761u) >> 20) & 1023u;
    for (;;){
      int prev = atomicCAS(&hkey[b*1024 + h], -1, l);
      if (prev == -1 || prev == l){ slot = b*1024 + (int)h; break; }
      h = (h+1) & 1023u;
    }
    atomicAdd(&hcnt[slot], 1);
    atomicMin(&hmin[slot], e);
  }
  __syncthreads();

  bool first = ok && (hmin[slot] == e);
  float a=0.f, iou=0.f; int nstar=0;
  if (first){
    float px = centers_ws[((size_t)b*LL + l)*4 + 0];
    float py = centers_ws[((size_t)b*LL + l)*4 + 1];
    float pz = centers_ws[((size_t)b*LL + l)*4 + 2];
    if (hcnt[slot] == 1){
      nstar = n;
    } else {
      float best = -1.f; int bidx = 0;
      #pragma unroll 1
      for (int nn=0;nn<32;++nn){
        float dx=gx[b*32+nn]-px, dy=gy[b*32+nn]-py, dz=gz[b*32+nn]-pz;
        float d2 = dx*dx+dy*dy+dz*dz;
        float io = expf(-d2/(2.f*gs[b*32+nn]*gs[b*32+nn]));
        if (io > best){ best=io; bidx=nn; }
      }
      nstar = bidx;
    }
    int gi = b*32 + nstar;
    float dx=gx[gi]-px, dy=gy[gi]-py, dz=gz[gi]-pz;
    float d2 = dx*dx+dy*dy+dz*dz;
    float sgv = gs[gi];
    iou = expf(-d2/(2.f*sgv*sgv));
    float z = logits_ws[(size_t)(b*NCLS + glab[gi])*LL + l];
    a = sigmoidf_(z) * expf(-3.f*d2/(sgv*sgv));
    atomicMax(&maxA[gi], __float_as_uint(a));
    atomicMax(&maxI[gi], __float_as_uint(iou));
  }
  __syncthreads();

  if (first){
    int gi = b*32 + nstar;
    float mA = __uint_as_float(maxA[gi]);
    float mI = __uint_as_float(maxI[gi]);
    float score = a*mI/(mA + 1e-9f);
    float z = logits_ws[(size_t)(b*NCLS + glab[gi])*LL + l];
    float p = sigmoidf_(z);
    float t2 = log1pf(expf(-fabsf(z)));
    float spz = fmaxf(z,0.f) + t2;
    float spm = fmaxf(-z,0.f) + t2;
    float corr = score*(score*spm + (1.f-score)*spz) - 0.75f*p*p*spz;
    float reg  = (1.f - iou)*score;
    atomicAdd(&accD, score);
    atomicAdd(&accC, corr + reg);
  }
  __syncthreads();
  if (tid==0) out[0] = (bg_sum[0] + accC) / accD;
}

extern "C" void kernel_launch(void* const* d_in, const int* in_sizes, int n_in,
                              void* d_out, int out_size, void* d_ws, size_t ws_size,
                              hipStream_t stream) {
  const float* feat  = (const float*)d_in[0];
  const float* cls_w = (const float*)d_in[1];
  const float* cls_b = (const float*)d_in[2];
  const float* off_w = (const float*)d_in[3];
  const float* off_b = (const float*)d_in[4];
  const float* labels= (const float*)d_in[5];
  float* out = (float*)d_out;

  float* logits_ws  = (float*)d_ws;                              // 2*5*L
  float* centers_ws = logits_ws + (size_t)NB*NCLS*LL;            // 2*L*4
  float* tv = centers_ws + (size_t)NB*LL*4;                      // 64*13
  int*   ti = (int*)(tv + 64*TOPKK);
  float* bg = (float*)(ti + 64*TOPKK);                           // [0]=bg,[1]=maxoff
  short* wA = (short*)(bg + 16);                                 // 96*64*8 bf16

  wtrans_kernel<<<24, 256, 0, stream>>>(cls_w, off_w, wA, bg);
  conv_mfma_kernel<<<dim3(16,16,2), 512, 0, stream>>>(
      feat, wA, cls_b, off_b, logits_ws, centers_ws, bg, (unsigned*)(bg+1));
  topk_box_kernel<<<64, 256, 0, stream>>>(
      logits_ws, centers_ws, labels, (const unsigned*)(bg+1), tv, ti);
  finalize_kernel<<<1, 1024, 0, stream>>>(
      logits_ws, centers_ws, labels, tv, ti, bg, out);
}